// Round 1
// baseline (482.224 us; speedup 1.0000x reference)
//
#include <hip/hip_runtime.h>

typedef __bf16 bf16x8 __attribute__((ext_vector_type(8)));
typedef float f32x4 __attribute__((ext_vector_type(4)));

#define B_ 4
#define T_ 2048
#define D_ 1024
#define H_ 16
#define HD_ 64
#define M_ 8192
// 1/sqrt(64) * log2(e), folded into Q so softmax uses exp2
#define QSCALE 0.1803368801111204f

__device__ __forceinline__ ushort f2b(float f) {
  union { float f; unsigned u; } v; v.f = f;
  unsigned u = v.u;
  return (ushort)((u + 0x7FFFu + ((u >> 16) & 1u)) >> 16);
}

__global__ __launch_bounds__(256) void cast_x_kernel(const float* __restrict__ x,
                                                     ushort* __restrict__ xb) {
  int idx = blockIdx.x * 256 + threadIdx.x;
  float4 v = ((const float4*)x)[idx];
  ushort4 o;
  o.x = f2b(v.x); o.y = f2b(v.y); o.z = f2b(v.z); o.w = f2b(v.w);
  ((ushort4*)xb)[idx] = o;
}

// 32x32 tiled transpose+cast: dst[n][k] = src[k][n], bf16 out
__global__ __launch_bounds__(256) void transpose_w_kernel(
    const float* __restrict__ wq, const float* __restrict__ wk,
    const float* __restrict__ wv, const float* __restrict__ wo,
    ushort* __restrict__ wt_qkv, ushort* __restrict__ wt_o) {
  __shared__ float tile[32][33];
  int z = blockIdx.z;
  const float* src = (z == 0) ? wq : (z == 1) ? wk : (z == 2) ? wv : wo;
  ushort* dst = (z < 3) ? (wt_qkv + (size_t)z * D_ * D_) : wt_o;
  int n0 = blockIdx.x * 32, k0 = blockIdx.y * 32;
  int tx = threadIdx.x & 31, ty = threadIdx.x >> 5;
  for (int i = 0; i < 4; i++) {
    int r = ty + i * 8;
    tile[r][tx] = src[(size_t)(k0 + r) * D_ + n0 + tx];
  }
  __syncthreads();
  for (int i = 0; i < 4; i++) {
    int r = ty + i * 8;
    dst[(size_t)(n0 + r) * D_ + k0 + tx] = f2b(tile[tx][r]);
  }
}

// C = A(MxK) * Bt(NxK)^T, 128x128 tile, BK=64, bf16 MFMA 16x16x32.
// mode 0: fused QKV epilogue (bias, Q scale, head-layout scatter, V transposed)
// mode 1: out-proj epilogue (bias, fp32 row-major)
__global__ __launch_bounds__(256) void gemm_kernel(
    const ushort* __restrict__ A, const ushort* __restrict__ Bt, int mode,
    const float* __restrict__ bias_q, const float* __restrict__ bias_k,
    const float* __restrict__ bias_v,
    ushort* __restrict__ qb, ushort* __restrict__ kb, ushort* __restrict__ vtb,
    float* __restrict__ outf) {
  __shared__ ushort As[128][72];  // +8 pad: 2-way bank aliasing only (free)
  __shared__ ushort Bs[128][72];
  int tid = threadIdx.x;
  int wave = tid >> 6, lane = tid & 63, lrow = lane >> 4, lcol = lane & 15;
  int m0 = blockIdx.y * 128, n0 = blockIdx.x * 128;
  int wm = (wave & 1) * 64, wn = (wave >> 1) * 64;

  f32x4 zero = {0.f, 0.f, 0.f, 0.f};
  f32x4 acc[4][4];
  for (int i = 0; i < 4; i++)
    for (int j = 0; j < 4; j++) acc[i][j] = zero;

  for (int k0 = 0; k0 < D_; k0 += 64) {
    for (int i = 0; i < 4; i++) {
      int c = i * 256 + tid;
      int r = c >> 3, col = (c & 7) * 8;
      *(uint4*)&As[r][col] = *(const uint4*)&A[(size_t)(m0 + r) * D_ + k0 + col];
      *(uint4*)&Bs[r][col] = *(const uint4*)&Bt[(size_t)(n0 + r) * D_ + k0 + col];
    }
    __syncthreads();
    for (int ks = 0; ks < 2; ks++) {
      bf16x8 af[4], bf[4];
      for (int mt = 0; mt < 4; mt++)
        af[mt] = *(const bf16x8*)&As[wm + mt * 16 + lcol][ks * 32 + lrow * 8];
      for (int nt = 0; nt < 4; nt++)
        bf[nt] = *(const bf16x8*)&Bs[wn + nt * 16 + lcol][ks * 32 + lrow * 8];
      for (int mt = 0; mt < 4; mt++)
        for (int nt = 0; nt < 4; nt++)
          acc[mt][nt] = __builtin_amdgcn_mfma_f32_16x16x32_bf16(
              af[mt], bf[nt], acc[mt][nt], 0, 0, 0);
    }
    __syncthreads();
  }

  if (mode == 0) {
    int proj = n0 >> 10;  // uniform per block (128 | 1024)
    const float* bias = (proj == 0) ? bias_q : (proj == 1) ? bias_k : bias_v;
    for (int mt = 0; mt < 4; mt++) {
      int gm0 = m0 + wm + mt * 16 + lrow * 4;  // 4 consecutive t, same b
      int b = gm0 >> 11, tp = gm0 & 2047;
      for (int nt = 0; nt < 4; nt++) {
        int gn = n0 + wn + nt * 16 + lcol;
        int inner = gn & 1023;
        int h = inner >> 6, hd = inner & 63;
        float bv = bias[inner];
        if (proj == 0) {
          size_t base = ((size_t)(b * H_ + h) * T_ + tp) * HD_ + hd;
          for (int r = 0; r < 4; r++)
            qb[base + (size_t)r * HD_] = f2b((acc[mt][nt][r] + bv) * QSCALE);
        } else if (proj == 1) {
          size_t base = ((size_t)(b * H_ + h) * T_ + tp) * HD_ + hd;
          for (int r = 0; r < 4; r++)
            kb[base + (size_t)r * HD_] = f2b(acc[mt][nt][r] + bv);
        } else {  // V stored transposed: (B,H,HD,T); 4 t's pack into ushort4
          ushort4 pk;
          pk.x = f2b(acc[mt][nt][0] + bv);
          pk.y = f2b(acc[mt][nt][1] + bv);
          pk.z = f2b(acc[mt][nt][2] + bv);
          pk.w = f2b(acc[mt][nt][3] + bv);
          *(ushort4*)&vtb[((size_t)(b * H_ + h) * HD_ + hd) * T_ + tp] = pk;
        }
      }
    }
  } else {
    for (int mt = 0; mt < 4; mt++) {
      int gm0 = m0 + wm + mt * 16 + lrow * 4;
      for (int nt = 0; nt < 4; nt++) {
        int gn = n0 + wn + nt * 16 + lcol;
        float bv = bias_q[gn];
        for (int r = 0; r < 4; r++)
          outf[(size_t)(gm0 + r) * D_ + gn] = acc[mt][nt][r] + bv;
      }
    }
  }
}

// Causal flash attention. Q tile 128 rows (32/wave), KV tile 64.
// Q pre-scaled by 1/sqrt(HD)*log2e -> exp2 softmax.
__global__ __launch_bounds__(256) void flash_kernel(
    const ushort* __restrict__ qb, const ushort* __restrict__ kb,
    const ushort* __restrict__ vtb, ushort* __restrict__ ob) {
  __shared__ ushort Ks[64][72];       // [kv][hd]
  __shared__ ushort Vs[64][72];       // [hd][kv]  (global V is pre-transposed)
  __shared__ ushort Ps[4][32][72];    // per-wave P strip: C-layout -> A-layout
  int tid = threadIdx.x;
  int wave = tid >> 6, lane = tid & 63, lrow = lane >> 4, lcol = lane & 15;
  int qt = blockIdx.x, bh = blockIdx.y;
  int b = bh >> 4, h = bh & 15;
  const ushort* qh = qb + (size_t)bh * T_ * HD_;
  const ushort* kh = kb + (size_t)bh * T_ * HD_;
  const ushort* vh = vtb + (size_t)bh * HD_ * T_;

  int qrb = qt * 128 + wave * 32;
  bf16x8 qf[2][2];  // A-frags for the wave's 32 Q rows, K=64
  for (int mt = 0; mt < 2; mt++)
    for (int ks = 0; ks < 2; ks++)
      qf[mt][ks] = *(const bf16x8*)&qh[(size_t)(qrb + mt * 16 + lcol) * HD_ +
                                       ks * 32 + lrow * 8];

  float m_run[2][4], l_run[2][4], alpha[2][4];
  f32x4 zero = {0.f, 0.f, 0.f, 0.f};
  f32x4 accO[2][4];
  for (int mt = 0; mt < 2; mt++)
    for (int r = 0; r < 4; r++) { m_run[mt][r] = -1e30f; l_run[mt][r] = 0.f; }
  for (int mt = 0; mt < 2; mt++)
    for (int n = 0; n < 4; n++) accO[mt][n] = zero;

  int jmax = 2 * qt + 1;
  for (int j = 0; j <= jmax; j++) {
    __syncthreads();  // prior iteration's Ks/Vs reads complete
    for (int i = 0; i < 2; i++) {
      int c = i * 256 + tid;
      int r = c >> 3, col = (c & 7) * 8;
      *(uint4*)&Ks[r][col] = *(const uint4*)&kh[(size_t)(j * 64 + r) * HD_ + col];
      *(uint4*)&Vs[r][col] = *(const uint4*)&vh[(size_t)r * T_ + j * 64 + col];
    }
    __syncthreads();

    // S = Q K^T (already in log2e units)
    f32x4 s[2][4];
    for (int mt = 0; mt < 2; mt++)
      for (int nt = 0; nt < 4; nt++) s[mt][nt] = zero;
    for (int ks = 0; ks < 2; ks++)
      for (int nt = 0; nt < 4; nt++) {
        bf16x8 kf = *(const bf16x8*)&Ks[nt * 16 + lcol][ks * 32 + lrow * 8];
        s[0][nt] = __builtin_amdgcn_mfma_f32_16x16x32_bf16(qf[0][ks], kf, s[0][nt], 0, 0, 0);
        s[1][nt] = __builtin_amdgcn_mfma_f32_16x16x32_bf16(qf[1][ks], kf, s[1][nt], 0, 0, 0);
      }

    if (j >= 2 * qt) {  // blocks overlapping the diagonal
      for (int mt = 0; mt < 2; mt++)
        for (int nt = 0; nt < 4; nt++)
          for (int r = 0; r < 4; r++) {
            int q_g = qrb + mt * 16 + lrow * 4 + r;
            int kv_g = j * 64 + nt * 16 + lcol;
            if (kv_g > q_g) s[mt][nt][r] = -1e30f;
          }
    }

    // online softmax (rows spread over 16 lanes of each lrow group)
    for (int mt = 0; mt < 2; mt++)
      for (int r = 0; r < 4; r++) {
        float mx = s[mt][0][r];
        for (int nt = 1; nt < 4; nt++) mx = fmaxf(mx, s[mt][nt][r]);
        for (int off = 8; off >= 1; off >>= 1) mx = fmaxf(mx, __shfl_xor(mx, off));
        float mn = fmaxf(m_run[mt][r], mx);
        alpha[mt][r] = exp2f(m_run[mt][r] - mn);
        m_run[mt][r] = mn;
        float rs = 0.f;
        for (int nt = 0; nt < 4; nt++) {
          float p = exp2f(s[mt][nt][r] - mn);
          s[mt][nt][r] = p;
          rs += p;
        }
        for (int off = 8; off >= 1; off >>= 1) rs += __shfl_xor(rs, off);
        l_run[mt][r] = l_run[mt][r] * alpha[mt][r] + rs;
      }

    // P -> LDS (C-layout write, A-layout read; same wave, no barrier needed)
    for (int mt = 0; mt < 2; mt++)
      for (int nt = 0; nt < 4; nt++)
        for (int r = 0; r < 4; r++)
          Ps[wave][mt * 16 + lrow * 4 + r][nt * 16 + lcol] = f2b(s[mt][nt][r]);

    for (int mt = 0; mt < 2; mt++)
      for (int n = 0; n < 4; n++)
        for (int r = 0; r < 4; r++) accO[mt][n][r] *= alpha[mt][r];

    // O += P V
    for (int ks = 0; ks < 2; ks++) {
      bf16x8 pf0 = *(const bf16x8*)&Ps[wave][lcol][ks * 32 + lrow * 8];
      bf16x8 pf1 = *(const bf16x8*)&Ps[wave][16 + lcol][ks * 32 + lrow * 8];
      for (int n = 0; n < 4; n++) {
        bf16x8 vf = *(const bf16x8*)&Vs[n * 16 + lcol][ks * 32 + lrow * 8];
        accO[0][n] = __builtin_amdgcn_mfma_f32_16x16x32_bf16(pf0, vf, accO[0][n], 0, 0, 0);
        accO[1][n] = __builtin_amdgcn_mfma_f32_16x16x32_bf16(pf1, vf, accO[1][n], 0, 0, 0);
      }
    }
  }

  // epilogue: O /= l, write (B,T,D) bf16
  for (int mt = 0; mt < 2; mt++)
    for (int r = 0; r < 4; r++) {
      float inv = 1.f / l_run[mt][r];
      int t = qt * 128 + wave * 32 + mt * 16 + lrow * 4 + r;
      size_t base = ((size_t)b * T_ + t) * D_ + h * HD_;
      for (int n = 0; n < 4; n++)
        ob[base + n * 16 + lcol] = f2b(accO[mt][n][r] * inv);
    }
}

extern "C" void kernel_launch(void* const* d_in, const int* in_sizes, int n_in,
                              void* d_out, int out_size, void* d_ws, size_t ws_size,
                              hipStream_t stream) {
  (void)in_sizes; (void)n_in; (void)out_size; (void)ws_size;
  const float* x  = (const float*)d_in[0];
  const float* wq = (const float*)d_in[1];
  const float* bq = (const float*)d_in[2];
  const float* wk = (const float*)d_in[3];
  const float* bk = (const float*)d_in[4];
  const float* wv = (const float*)d_in[5];
  const float* bv = (const float*)d_in[6];
  const float* wo = (const float*)d_in[7];
  const float* bo = (const float*)d_in[8];
  float* out = (float*)d_out;

  char* ws = (char*)d_ws;
  ushort* xb     = (ushort*)(ws);              // 16 MB  x as bf16 (M x K)
  ushort* wt_qkv = (ushort*)(ws + 16777216);   // 6 MB   [wq|wk|wv]^T (3072 x 1024)
  ushort* wt_o   = (ushort*)(ws + 23068672);   // 2 MB   wo^T
  ushort* qb     = (ushort*)(ws + 25165824);   // 16 MB  Q (B,H,T,HD), pre-scaled
  ushort* kb     = (ushort*)(ws + 41943040);   // 16 MB  K (B,H,T,HD)
  ushort* vtb    = (ushort*)(ws + 58720256);   // 16 MB  V (B,H,HD,T)
  ushort* ob     = (ushort*)(ws + 75497472);   // 16 MB  attn out (B,T,D)

  cast_x_kernel<<<8192, 256, 0, stream>>>(x, xb);
  transpose_w_kernel<<<dim3(32, 32, 4), 256, 0, stream>>>(wq, wk, wv, wo, wt_qkv, wt_o);
  gemm_kernel<<<dim3(24, 64), 256, 0, stream>>>(xb, wt_qkv, 0, bq, bk, bv, qb, kb, vtb, nullptr);
  flash_kernel<<<dim3(16, 64), 256, 0, stream>>>(qb, kb, vtb, ob);
  gemm_kernel<<<dim3(8, 64), 256, 0, stream>>>(ob, wt_o, 1, bo, nullptr, nullptr,
                                               nullptr, nullptr, nullptr, out);
}

// Round 2
// 374.330 us; speedup vs baseline: 1.2882x; 1.2882x over previous
//
#include <hip/hip_runtime.h>

typedef __bf16 bf16x8 __attribute__((ext_vector_type(8)));
typedef float f32x4 __attribute__((ext_vector_type(4)));

#define B_ 4
#define T_ 2048
#define D_ 1024
#define H_ 16
#define HD_ 64
#define M_ 8192
// 1/sqrt(64) * log2(e), folded into Q so softmax uses exp2
#define QSCALE 0.1803368801111204f

__device__ __forceinline__ ushort f2b(float f) {
  union { float f; unsigned u; } v; v.f = f;
  unsigned u = v.u;
  return (ushort)((u + 0x7FFFu + ((u >> 16) & 1u)) >> 16);
}

__global__ __launch_bounds__(256) void cast_x_kernel(const float* __restrict__ x,
                                                     ushort* __restrict__ xb) {
  int idx = blockIdx.x * 256 + threadIdx.x;
  float4 v = ((const float4*)x)[idx];
  ushort4 o;
  o.x = f2b(v.x); o.y = f2b(v.y); o.z = f2b(v.z); o.w = f2b(v.w);
  ((ushort4*)xb)[idx] = o;
}

// 32x32 tiled transpose+cast: dst[n][k] = src[k][n], bf16 out
__global__ __launch_bounds__(256) void transpose_w_kernel(
    const float* __restrict__ wq, const float* __restrict__ wk,
    const float* __restrict__ wv, const float* __restrict__ wo,
    ushort* __restrict__ wt_qkv, ushort* __restrict__ wt_o) {
  __shared__ float tile[32][33];
  int z = blockIdx.z;
  const float* src = (z == 0) ? wq : (z == 1) ? wk : (z == 2) ? wv : wo;
  ushort* dst = (z < 3) ? (wt_qkv + (size_t)z * D_ * D_) : wt_o;
  int n0 = blockIdx.x * 32, k0 = blockIdx.y * 32;
  int tx = threadIdx.x & 31, ty = threadIdx.x >> 5;
  for (int i = 0; i < 4; i++) {
    int r = ty + i * 8;
    tile[r][tx] = src[(size_t)(k0 + r) * D_ + n0 + tx];
  }
  __syncthreads();
  for (int i = 0; i < 4; i++) {
    int r = ty + i * 8;
    dst[(size_t)(n0 + r) * D_ + k0 + tx] = f2b(tile[tx][r]);
  }
}

// C = A(MxK) * Bt(NxK)^T, 128x128 tile, BK=64, bf16 MFMA 16x16x32.
// mode 0: fused QKV epilogue (bias, Q scale, head-layout scatter, V transposed)
// mode 1: out-proj epilogue (bias, fp32 row-major)
__global__ __launch_bounds__(256) void gemm_kernel(
    const ushort* __restrict__ A, const ushort* __restrict__ Bt, int mode,
    const float* __restrict__ bias_q, const float* __restrict__ bias_k,
    const float* __restrict__ bias_v,
    ushort* __restrict__ qb, ushort* __restrict__ kb, ushort* __restrict__ vtb,
    float* __restrict__ outf) {
  __shared__ ushort As[128][72];  // +8 pad: 2-way bank aliasing only (free)
  __shared__ ushort Bs[128][72];
  int tid = threadIdx.x;
  int wave = tid >> 6, lane = tid & 63, lrow = lane >> 4, lcol = lane & 15;
  int m0 = blockIdx.y * 128, n0 = blockIdx.x * 128;
  int wm = (wave & 1) * 64, wn = (wave >> 1) * 64;

  f32x4 zero = {0.f, 0.f, 0.f, 0.f};
  f32x4 acc[4][4];
  for (int i = 0; i < 4; i++)
    for (int j = 0; j < 4; j++) acc[i][j] = zero;

  for (int k0 = 0; k0 < D_; k0 += 64) {
    for (int i = 0; i < 4; i++) {
      int c = i * 256 + tid;
      int r = c >> 3, col = (c & 7) * 8;
      *(uint4*)&As[r][col] = *(const uint4*)&A[(size_t)(m0 + r) * D_ + k0 + col];
      *(uint4*)&Bs[r][col] = *(const uint4*)&Bt[(size_t)(n0 + r) * D_ + k0 + col];
    }
    __syncthreads();
    for (int ks = 0; ks < 2; ks++) {
      bf16x8 af[4], bf[4];
      for (int mt = 0; mt < 4; mt++)
        af[mt] = *(const bf16x8*)&As[wm + mt * 16 + lcol][ks * 32 + lrow * 8];
      for (int nt = 0; nt < 4; nt++)
        bf[nt] = *(const bf16x8*)&Bs[wn + nt * 16 + lcol][ks * 32 + lrow * 8];
      for (int mt = 0; mt < 4; mt++)
        for (int nt = 0; nt < 4; nt++)
          acc[mt][nt] = __builtin_amdgcn_mfma_f32_16x16x32_bf16(
              af[mt], bf[nt], acc[mt][nt], 0, 0, 0);
    }
    __syncthreads();
  }

  if (mode == 0) {
    int proj = n0 >> 10;  // uniform per block (128 | 1024)
    const float* bias = (proj == 0) ? bias_q : (proj == 1) ? bias_k : bias_v;
    for (int mt = 0; mt < 4; mt++) {
      int gm0 = m0 + wm + mt * 16 + lrow * 4;  // 4 consecutive t, same b
      int b = gm0 >> 11, tp = gm0 & 2047;
      for (int nt = 0; nt < 4; nt++) {
        int gn = n0 + wn + nt * 16 + lcol;
        int inner = gn & 1023;
        int h = inner >> 6, hd = inner & 63;
        float bv = bias[inner];
        if (proj == 0) {
          size_t base = ((size_t)(b * H_ + h) * T_ + tp) * HD_ + hd;
          for (int r = 0; r < 4; r++)
            qb[base + (size_t)r * HD_] = f2b((acc[mt][nt][r] + bv) * QSCALE);
        } else if (proj == 1) {
          size_t base = ((size_t)(b * H_ + h) * T_ + tp) * HD_ + hd;
          for (int r = 0; r < 4; r++)
            kb[base + (size_t)r * HD_] = f2b(acc[mt][nt][r] + bv);
        } else {  // V stored transposed: (B,H,HD,T); 4 t's pack into ushort4
          ushort4 pk;
          pk.x = f2b(acc[mt][nt][0] + bv);
          pk.y = f2b(acc[mt][nt][1] + bv);
          pk.z = f2b(acc[mt][nt][2] + bv);
          pk.w = f2b(acc[mt][nt][3] + bv);
          *(ushort4*)&vtb[((size_t)(b * H_ + h) * HD_ + hd) * T_ + tp] = pk;
        }
      }
    }
  } else {
    for (int mt = 0; mt < 4; mt++) {
      int gm0 = m0 + wm + mt * 16 + lrow * 4;
      for (int nt = 0; nt < 4; nt++) {
        int gn = n0 + wn + nt * 16 + lcol;
        float bv = bias_q[gn];
        for (int r = 0; r < 4; r++)
          outf[(size_t)(gm0 + r) * D_ + gn] = acc[mt][nt][r] + bv;
      }
    }
  }
}

// Causal flash attention, S^T formulation: S^T = K Q^T so q is the lane
// (column) dim of the MFMA C-layout. Softmax over kv = local regs + 2
// shuffles; P^T packs to ushort4 LDS writes and reads back as b128 A-frags.
// Q pre-scaled by 1/sqrt(HD)*log2e -> exp2 softmax.
__global__ __launch_bounds__(256) void flash_kernel(
    const ushort* __restrict__ qb, const ushort* __restrict__ kb,
    const ushort* __restrict__ vtb, ushort* __restrict__ ob) {
  __shared__ ushort Ks[64][72];       // [kv][hd]
  __shared__ ushort Vs[64][72];       // [hd][kv]  (global V is pre-transposed)
  __shared__ ushort Ps[4][32][72];    // per-wave P^T strip: [q][kv]
  int tid = threadIdx.x;
  int wave = tid >> 6, lane = tid & 63, lrow = lane >> 4, lcol = lane & 15;
  int qt = (gridDim.x - 1) - blockIdx.x;  // longest blocks dispatch first
  int bh = blockIdx.y;
  int b = bh >> 4, h = bh & 15;
  const ushort* qh = qb + (size_t)bh * T_ * HD_;
  const ushort* kh = kb + (size_t)bh * T_ * HD_;
  const ushort* vh = vtb + (size_t)bh * HD_ * T_;

  int q0w = qt * 128 + wave * 32;
  // Q as B-operand frags: B[n=q][k=hd], lane holds [q=nt*16+lcol][hd=lrow*8+j]
  bf16x8 qf[2][2];
  for (int nt = 0; nt < 2; nt++)
    for (int ks = 0; ks < 2; ks++)
      qf[nt][ks] = *(const bf16x8*)&qh[(size_t)(q0w + nt * 16 + lcol) * HD_ +
                                       ks * 32 + lrow * 8];

  float m_run[2] = {-1e30f, -1e30f}, l_run[2] = {0.f, 0.f};
  f32x4 zero = {0.f, 0.f, 0.f, 0.f};
  f32x4 accO[2][4];  // [q-tile][hd-tile]
  for (int qa = 0; qa < 2; qa++)
    for (int n = 0; n < 4; n++) accO[qa][n] = zero;

  int c1 = 256 + tid;
  int r0 = tid >> 3, col0 = (tid & 7) * 8;
  int r1 = c1 >> 3, col1 = (c1 & 7) * 8;

  int jmax = 2 * qt + 1;
  // prefetch tile j=0 into registers
  uint4 kreg0 = *(const uint4*)&kh[(size_t)r0 * HD_ + col0];
  uint4 kreg1 = *(const uint4*)&kh[(size_t)r1 * HD_ + col1];
  uint4 vreg0 = *(const uint4*)&vh[(size_t)r0 * T_ + col0];
  uint4 vreg1 = *(const uint4*)&vh[(size_t)r1 * T_ + col1];

  for (int j = 0; j <= jmax; j++) {
    __syncthreads();  // prior iteration's Ks/Vs reads complete
    *(uint4*)&Ks[r0][col0] = kreg0;
    *(uint4*)&Ks[r1][col1] = kreg1;
    *(uint4*)&Vs[r0][col0] = vreg0;
    *(uint4*)&Vs[r1][col1] = vreg1;
    __syncthreads();
    if (j < jmax) {  // prefetch next tile; latency hides under compute
      int jn = j + 1;
      kreg0 = *(const uint4*)&kh[(size_t)(jn * 64 + r0) * HD_ + col0];
      kreg1 = *(const uint4*)&kh[(size_t)(jn * 64 + r1) * HD_ + col1];
      vreg0 = *(const uint4*)&vh[(size_t)r0 * T_ + jn * 64 + col0];
      vreg1 = *(const uint4*)&vh[(size_t)r1 * T_ + jn * 64 + col1];
    }

    // S^T = K Q^T: st[mt][nt], lane holds [kv=mt*16+lrow*4+r][q=nt*16+lcol]
    f32x4 st[4][2];
    for (int mt = 0; mt < 4; mt++)
      for (int nt = 0; nt < 2; nt++) st[mt][nt] = zero;
    for (int ks = 0; ks < 2; ks++)
      for (int mt = 0; mt < 4; mt++) {
        bf16x8 kf = *(const bf16x8*)&Ks[mt * 16 + lcol][ks * 32 + lrow * 8];
        st[mt][0] = __builtin_amdgcn_mfma_f32_16x16x32_bf16(kf, qf[0][ks], st[mt][0], 0, 0, 0);
        st[mt][1] = __builtin_amdgcn_mfma_f32_16x16x32_bf16(kf, qf[1][ks], st[mt][1], 0, 0, 0);
      }

    if (j >= 2 * qt) {  // tiles overlapping the diagonal
      for (int mt = 0; mt < 4; mt++)
        for (int nt = 0; nt < 2; nt++)
          for (int r = 0; r < 4; r++) {
            int kv_g = j * 64 + mt * 16 + lrow * 4 + r;
            int q_g = q0w + nt * 16 + lcol;
            if (kv_g > q_g) st[mt][nt][r] = -1e30f;
          }
    }

    // online softmax: 16 local kv values per q, then xor16+xor32 reduce
    float alpha[2];
    for (int nt = 0; nt < 2; nt++) {
      float mx = st[0][nt][0];
      for (int mt = 0; mt < 4; mt++)
        for (int r = 0; r < 4; r++) mx = fmaxf(mx, st[mt][nt][r]);
      mx = fmaxf(mx, __shfl_xor(mx, 16));
      mx = fmaxf(mx, __shfl_xor(mx, 32));
      float mn = fmaxf(m_run[nt], mx);
      alpha[nt] = exp2f(m_run[nt] - mn);
      m_run[nt] = mn;
      float rs = 0.f;
      for (int mt = 0; mt < 4; mt++)
        for (int r = 0; r < 4; r++) {
          float p = exp2f(st[mt][nt][r] - mn);
          st[mt][nt][r] = p;
          rs += p;
        }
      rs += __shfl_xor(rs, 16);
      rs += __shfl_xor(rs, 32);
      l_run[nt] = l_run[nt] * alpha[nt] + rs;
    }

    // P^T -> LDS, packed b64 writes (4 consecutive kv per lane per q)
    for (int mt = 0; mt < 4; mt++)
      for (int nt = 0; nt < 2; nt++) {
        ushort4 pk;
        pk.x = f2b(st[mt][nt][0]);
        pk.y = f2b(st[mt][nt][1]);
        pk.z = f2b(st[mt][nt][2]);
        pk.w = f2b(st[mt][nt][3]);
        *(ushort4*)&Ps[wave][nt * 16 + lcol][mt * 16 + lrow * 4] = pk;
      }

    // rescale accO rows (q = qa*16 + lrow*4 + r; alpha lives in lane q&15)
    for (int qa = 0; qa < 2; qa++)
      for (int r = 0; r < 4; r++) {
        float a = __shfl(alpha[qa], lrow * 4 + r);
        for (int n = 0; n < 4; n++) accO[qa][n][r] *= a;
      }

    // O += P V  (P as A-operand: b128 reads from Ps; same wave, no barrier)
    for (int ks = 0; ks < 2; ks++) {
      bf16x8 pf0 = *(const bf16x8*)&Ps[wave][lcol][ks * 32 + lrow * 8];
      bf16x8 pf1 = *(const bf16x8*)&Ps[wave][16 + lcol][ks * 32 + lrow * 8];
      for (int n = 0; n < 4; n++) {
        bf16x8 vf = *(const bf16x8*)&Vs[n * 16 + lcol][ks * 32 + lrow * 8];
        accO[0][n] = __builtin_amdgcn_mfma_f32_16x16x32_bf16(pf0, vf, accO[0][n], 0, 0, 0);
        accO[1][n] = __builtin_amdgcn_mfma_f32_16x16x32_bf16(pf1, vf, accO[1][n], 0, 0, 0);
      }
    }
  }

  // epilogue: O /= l (l lives in lane q&15), write (B,T,D) bf16
  for (int qa = 0; qa < 2; qa++)
    for (int r = 0; r < 4; r++) {
      float linv = 1.f / __shfl(l_run[qa], lrow * 4 + r);
      int t = q0w + qa * 16 + lrow * 4 + r;
      size_t base = ((size_t)b * T_ + t) * D_ + h * HD_;
      for (int n = 0; n < 4; n++)
        ob[base + n * 16 + lcol] = f2b(accO[qa][n][r] * linv);
    }
}

extern "C" void kernel_launch(void* const* d_in, const int* in_sizes, int n_in,
                              void* d_out, int out_size, void* d_ws, size_t ws_size,
                              hipStream_t stream) {
  (void)in_sizes; (void)n_in; (void)out_size; (void)ws_size;
  const float* x  = (const float*)d_in[0];
  const float* wq = (const float*)d_in[1];
  const float* bq = (const float*)d_in[2];
  const float* wk = (const float*)d_in[3];
  const float* bk = (const float*)d_in[4];
  const float* wv = (const float*)d_in[5];
  const float* bv = (const float*)d_in[6];
  const float* wo = (const float*)d_in[7];
  const float* bo = (const float*)d_in[8];
  float* out = (float*)d_out;

  char* ws = (char*)d_ws;
  ushort* xb     = (ushort*)(ws);              // 16 MB  x as bf16 (M x K)
  ushort* wt_qkv = (ushort*)(ws + 16777216);   // 6 MB   [wq|wk|wv]^T (3072 x 1024)
  ushort* wt_o   = (ushort*)(ws + 23068672);   // 2 MB   wo^T
  ushort* qb     = (ushort*)(ws + 25165824);   // 16 MB  Q (B,H,T,HD), pre-scaled
  ushort* kb     = (ushort*)(ws + 41943040);   // 16 MB  K (B,H,T,HD)
  ushort* vtb    = (ushort*)(ws + 58720256);   // 16 MB  V (B,H,HD,T)
  ushort* ob     = (ushort*)(ws + 75497472);   // 16 MB  attn out (B,T,D)

  cast_x_kernel<<<8192, 256, 0, stream>>>(x, xb);
  transpose_w_kernel<<<dim3(32, 32, 4), 256, 0, stream>>>(wq, wk, wv, wo, wt_qkv, wt_o);
  gemm_kernel<<<dim3(24, 64), 256, 0, stream>>>(xb, wt_qkv, 0, bq, bk, bv, qb, kb, vtb, nullptr);
  flash_kernel<<<dim3(16, 64), 256, 0, stream>>>(qb, kb, vtb, ob);
  gemm_kernel<<<dim3(8, 64), 256, 0, stream>>>(ob, wt_o, 1, bo, nullptr, nullptr,
                                               nullptr, nullptr, nullptr, out);
}

// Round 3
// 288.599 us; speedup vs baseline: 1.6709x; 1.2971x over previous
//
#include <hip/hip_runtime.h>

typedef __bf16 bf16x8 __attribute__((ext_vector_type(8)));
typedef float f32x4 __attribute__((ext_vector_type(4)));

#define B_ 4
#define T_ 2048
#define D_ 1024
#define H_ 16
#define HD_ 64
#define M_ 8192
// 1/sqrt(64) * log2(e), folded into Q so softmax uses exp2
#define QSCALE 0.1803368801111204f

__device__ __forceinline__ ushort f2b(float f) {
  union { float f; unsigned u; } v; v.f = f;
  unsigned u = v.u;
  return (ushort)((u + 0x7FFFu + ((u >> 16) & 1u)) >> 16);
}

// pack two floats to bf16 pair (round-half-up: +0x8000 then take hi16)
__device__ __forceinline__ unsigned pkbf(float a, float b) {
  union { float f; unsigned u; } va, vb; va.f = a; vb.f = b;
  return __builtin_amdgcn_perm(vb.u + 0x8000u, va.u + 0x8000u, 0x07060302u);
}

__global__ __launch_bounds__(256) void cast_x_kernel(const float* __restrict__ x,
                                                     ushort* __restrict__ xb) {
  int idx = blockIdx.x * 256 + threadIdx.x;
  float4 v = ((const float4*)x)[idx];
  ushort4 o;
  o.x = f2b(v.x); o.y = f2b(v.y); o.z = f2b(v.z); o.w = f2b(v.w);
  ((ushort4*)xb)[idx] = o;
}

// 32x32 tiled transpose+cast: dst[n][k] = src[k][n], bf16 out
__global__ __launch_bounds__(256) void transpose_w_kernel(
    const float* __restrict__ wq, const float* __restrict__ wk,
    const float* __restrict__ wv, const float* __restrict__ wo,
    ushort* __restrict__ wt_qkv, ushort* __restrict__ wt_o) {
  __shared__ float tile[32][33];
  int z = blockIdx.z;
  const float* src = (z == 0) ? wq : (z == 1) ? wk : (z == 2) ? wv : wo;
  ushort* dst = (z < 3) ? (wt_qkv + (size_t)z * D_ * D_) : wt_o;
  int n0 = blockIdx.x * 32, k0 = blockIdx.y * 32;
  int tx = threadIdx.x & 31, ty = threadIdx.x >> 5;
  for (int i = 0; i < 4; i++) {
    int r = ty + i * 8;
    tile[r][tx] = src[(size_t)(k0 + r) * D_ + n0 + tx];
  }
  __syncthreads();
  for (int i = 0; i < 4; i++) {
    int r = ty + i * 8;
    dst[(size_t)(n0 + r) * D_ + k0 + tx] = f2b(tile[tx][r]);
  }
}

// C = A(MxK) * Bt(NxK)^T, 128x128 tile, BK=64, bf16 MFMA 16x16x32.
// mode 0: fused QKV epilogue (bias, Q scale, head-layout scatter, V transposed)
// mode 1: out-proj epilogue (bias, fp32 row-major)
__global__ __launch_bounds__(256) void gemm_kernel(
    const ushort* __restrict__ A, const ushort* __restrict__ Bt, int mode,
    const float* __restrict__ bias_q, const float* __restrict__ bias_k,
    const float* __restrict__ bias_v,
    ushort* __restrict__ qb, ushort* __restrict__ kb, ushort* __restrict__ vtb,
    float* __restrict__ outf) {
  __shared__ ushort As[128][72];
  __shared__ ushort Bs[128][72];
  int tid = threadIdx.x;
  int wave = tid >> 6, lane = tid & 63, lrow = lane >> 4, lcol = lane & 15;
  int m0 = blockIdx.y * 128, n0 = blockIdx.x * 128;
  int wm = (wave & 1) * 64, wn = (wave >> 1) * 64;

  f32x4 zero = {0.f, 0.f, 0.f, 0.f};
  f32x4 acc[4][4];
  for (int i = 0; i < 4; i++)
    for (int j = 0; j < 4; j++) acc[i][j] = zero;

  for (int k0 = 0; k0 < D_; k0 += 64) {
    for (int i = 0; i < 4; i++) {
      int c = i * 256 + tid;
      int r = c >> 3, col = (c & 7) * 8;
      *(uint4*)&As[r][col] = *(const uint4*)&A[(size_t)(m0 + r) * D_ + k0 + col];
      *(uint4*)&Bs[r][col] = *(const uint4*)&Bt[(size_t)(n0 + r) * D_ + k0 + col];
    }
    __syncthreads();
    for (int ks = 0; ks < 2; ks++) {
      bf16x8 af[4], bf[4];
      for (int mt = 0; mt < 4; mt++)
        af[mt] = *(const bf16x8*)&As[wm + mt * 16 + lcol][ks * 32 + lrow * 8];
      for (int nt = 0; nt < 4; nt++)
        bf[nt] = *(const bf16x8*)&Bs[wn + nt * 16 + lcol][ks * 32 + lrow * 8];
      for (int mt = 0; mt < 4; mt++)
        for (int nt = 0; nt < 4; nt++)
          acc[mt][nt] = __builtin_amdgcn_mfma_f32_16x16x32_bf16(
              af[mt], bf[nt], acc[mt][nt], 0, 0, 0);
    }
    __syncthreads();
  }

  if (mode == 0) {
    int proj = n0 >> 10;  // uniform per block (128 | 1024)
    const float* bias = (proj == 0) ? bias_q : (proj == 1) ? bias_k : bias_v;
    for (int mt = 0; mt < 4; mt++) {
      int gm0 = m0 + wm + mt * 16 + lrow * 4;  // 4 consecutive t, same b
      int b = gm0 >> 11, tp = gm0 & 2047;
      for (int nt = 0; nt < 4; nt++) {
        int gn = n0 + wn + nt * 16 + lcol;
        int inner = gn & 1023;
        int h = inner >> 6, hd = inner & 63;
        float bv = bias[inner];
        if (proj == 0) {
          size_t base = ((size_t)(b * H_ + h) * T_ + tp) * HD_ + hd;
          for (int r = 0; r < 4; r++)
            qb[base + (size_t)r * HD_] = f2b((acc[mt][nt][r] + bv) * QSCALE);
        } else if (proj == 1) {
          size_t base = ((size_t)(b * H_ + h) * T_ + tp) * HD_ + hd;
          for (int r = 0; r < 4; r++)
            kb[base + (size_t)r * HD_] = f2b(acc[mt][nt][r] + bv);
        } else {  // V stored transposed: (B,H,HD,T); 4 t's pack into ushort4
          ushort4 pk;
          pk.x = f2b(acc[mt][nt][0] + bv);
          pk.y = f2b(acc[mt][nt][1] + bv);
          pk.z = f2b(acc[mt][nt][2] + bv);
          pk.w = f2b(acc[mt][nt][3] + bv);
          *(ushort4*)&vtb[((size_t)(b * H_ + h) * HD_ + hd) * T_ + tp] = pk;
        }
      }
    }
  } else {
    for (int mt = 0; mt < 4; mt++) {
      int gm0 = m0 + wm + mt * 16 + lrow * 4;
      for (int nt = 0; nt < 4; nt++) {
        int gn = n0 + wn + nt * 16 + lcol;
        float bv = bias_q[gn];
        for (int r = 0; r < 4; r++)
          outf[(size_t)(gm0 + r) * D_ + gn] = acc[mt][nt][r] + bv;
      }
    }
  }
}

// Causal flash attention, balanced-pair scheduling + S^T/O^T formulation.
// Block p handles q-tiles (31-p, p) of 64 rows each -> every block does
// exactly 33 KV-tile iterations (no tail). Each of 4 waves owns 16 q rows.
// S^T = K Q^T puts q in lcol; O^T = V P^T keeps q in lcol, so softmax
// stats (m,l,alpha) are per-lane scalars: zero cross-lane ops for rescale.
// Q pre-scaled by 1/sqrt(HD)*log2e -> exp2 softmax.
__global__ __launch_bounds__(256) void flash_kernel(
    const ushort* __restrict__ qb, const ushort* __restrict__ kb,
    const ushort* __restrict__ vtb, ushort* __restrict__ ob) {
  __shared__ ushort Ks[64][80];      // [kv][hd], stride 80: <=4-way banks
  __shared__ ushort Vs[64][80];      // [hd][kv]  (global V pre-transposed)
  __shared__ ushort Ps[4][16][80];   // per-wave P^T strip: [q][kv]
  int tid = threadIdx.x;
  int wave = tid >> 6, lane = tid & 63, lrow = lane >> 4, lcol = lane & 15;
  int p = blockIdx.x;                // pair index: q-tiles (31-p, p)
  int bh = blockIdx.y;
  int b = bh >> 4, h = bh & 15;
  const ushort* qh = qb + (size_t)bh * T_ * HD_;
  const ushort* kh = kb + (size_t)bh * T_ * HD_;
  const ushort* vh = vtb + (size_t)bh * HD_ * T_;

  int r0 = tid >> 3, cb0 = (tid & 7) * 8;   // staging: row, col-chunk
  // prefetch KV tile j=0 into registers
  uint4 kr0 = *(const uint4*)&kh[(size_t)r0 * HD_ + cb0];
  uint4 kr1 = *(const uint4*)&kh[(size_t)(r0 + 32) * HD_ + cb0];
  uint4 vr0 = *(const uint4*)&vh[(size_t)r0 * T_ + cb0];
  uint4 vr1 = *(const uint4*)&vh[(size_t)(r0 + 32) * T_ + cb0];

  f32x4 zero = {0.f, 0.f, 0.f, 0.f};

  for (int pass = 0; pass < 2; pass++) {
    int qtile = pass ? p : (31 - p);
    int q0w = qtile * 64 + wave * 16;
    // Q as B-operand frags: [n=q=lcol][k=hd]
    bf16x8 qf[2];
    for (int ks = 0; ks < 2; ks++)
      qf[ks] = *(const bf16x8*)&qh[(size_t)(q0w + lcol) * HD_ + ks * 32 + lrow * 8];

    float m_run = -1e30f, l_run = 0.f;
    f32x4 accO[4];  // O^T frags: [hd-tile]; rows=hd, cols=q=lcol
    for (int mt = 0; mt < 4; mt++) accO[mt] = zero;

    for (int j = 0; j <= qtile; j++) {
      __syncthreads();  // all waves done reading previous tile
      *(uint4*)&Ks[r0][cb0] = kr0;
      *(uint4*)&Ks[r0 + 32][cb0] = kr1;
      *(uint4*)&Vs[r0][cb0] = vr0;
      *(uint4*)&Vs[r0 + 32][cb0] = vr1;
      __syncthreads();

      // prefetch next tile (next j, or pass 1's tile 0)
      if (j < qtile || pass == 0) {
        int jn = (j < qtile) ? j + 1 : 0;
        kr0 = *(const uint4*)&kh[(size_t)(jn * 64 + r0) * HD_ + cb0];
        kr1 = *(const uint4*)&kh[(size_t)(jn * 64 + r0 + 32) * HD_ + cb0];
        vr0 = *(const uint4*)&vh[(size_t)r0 * T_ + jn * 64 + cb0];
        vr1 = *(const uint4*)&vh[(size_t)(r0 + 32) * T_ + jn * 64 + cb0];
      }

      // S^T = K Q^T: st[mt], lane holds [kv=mt*16+lrow*4+r][q=lcol]
      f32x4 st[4];
      for (int mt = 0; mt < 4; mt++) st[mt] = zero;
      for (int ks = 0; ks < 2; ks++)
        for (int mt = 0; mt < 4; mt++) {
          bf16x8 kf = *(const bf16x8*)&Ks[mt * 16 + lcol][ks * 32 + lrow * 8];
          st[mt] = __builtin_amdgcn_mfma_f32_16x16x32_bf16(kf, qf[ks], st[mt], 0, 0, 0);
        }

      if (j == qtile) {  // diagonal tile: causal mask
        int q_g = q0w + lcol;
        for (int mt = 0; mt < 4; mt++)
          for (int r = 0; r < 4; r++) {
            int kv_g = j * 64 + mt * 16 + lrow * 4 + r;
            if (kv_g > q_g) st[mt][r] = -1e30f;
          }
      }

      // online softmax: 16 local kv per lane, then xor16+xor32 reduce
      float mx = fmaxf(
          fmaxf(fmaxf(fmaxf(st[0][0], st[0][1]), fmaxf(st[0][2], st[0][3])),
                fmaxf(fmaxf(st[1][0], st[1][1]), fmaxf(st[1][2], st[1][3]))),
          fmaxf(fmaxf(fmaxf(st[2][0], st[2][1]), fmaxf(st[2][2], st[2][3])),
                fmaxf(fmaxf(st[3][0], st[3][1]), fmaxf(st[3][2], st[3][3]))));
      mx = fmaxf(mx, __shfl_xor(mx, 16));
      mx = fmaxf(mx, __shfl_xor(mx, 32));
      float mn = fmaxf(m_run, mx);
      float alpha = __builtin_amdgcn_exp2f(m_run - mn);
      m_run = mn;
      float rs = 0.f;
      for (int mt = 0; mt < 4; mt++)
        for (int r = 0; r < 4; r++) {
          float pv = __builtin_amdgcn_exp2f(st[mt][r] - mn);
          st[mt][r] = pv;
          rs += pv;
        }
      rs += __shfl_xor(rs, 16);
      rs += __shfl_xor(rs, 32);
      l_run = l_run * alpha + rs;

      // P^T -> LDS (packed v_perm bf16 pairs; same-wave write->read)
      for (int mt = 0; mt < 4; mt++) {
        uint2 pk;
        pk.x = pkbf(st[mt][0], st[mt][1]);
        pk.y = pkbf(st[mt][2], st[mt][3]);
        *(uint2*)&Ps[wave][lcol][mt * 16 + lrow * 4] = pk;
      }

      // rescale O^T (alpha is per-lane: q=lcol)
      for (int mt = 0; mt < 4; mt++)
        for (int r = 0; r < 4; r++) accO[mt][r] *= alpha;

      // O^T += V P^T  (A=V[m=hd][k=kv], B=P^T[n=q][k=kv])
      for (int ks = 0; ks < 2; ks++) {
        bf16x8 pf = *(const bf16x8*)&Ps[wave][lcol][ks * 32 + lrow * 8];
        for (int mt = 0; mt < 4; mt++) {
          bf16x8 vf = *(const bf16x8*)&Vs[mt * 16 + lcol][ks * 32 + lrow * 8];
          accO[mt] = __builtin_amdgcn_mfma_f32_16x16x32_bf16(vf, pf, accO[mt], 0, 0, 0);
        }
      }
    }

    // epilogue: O /= l (per-lane), write (B,T,D) bf16, ushort4 stores
    float linv = 1.f / l_run;
    int t = q0w + lcol;
    size_t base = ((size_t)b * T_ + t) * D_ + h * HD_;
    for (int mt = 0; mt < 4; mt++) {
      uint2 pk;
      pk.x = pkbf(accO[mt][0] * linv, accO[mt][1] * linv);
      pk.y = pkbf(accO[mt][2] * linv, accO[mt][3] * linv);
      *(uint2*)&ob[base + mt * 16 + lrow * 4] = pk;
    }
  }
}

extern "C" void kernel_launch(void* const* d_in, const int* in_sizes, int n_in,
                              void* d_out, int out_size, void* d_ws, size_t ws_size,
                              hipStream_t stream) {
  (void)in_sizes; (void)n_in; (void)out_size; (void)ws_size;
  const float* x  = (const float*)d_in[0];
  const float* wq = (const float*)d_in[1];
  const float* bq = (const float*)d_in[2];
  const float* wk = (const float*)d_in[3];
  const float* bk = (const float*)d_in[4];
  const float* wv = (const float*)d_in[5];
  const float* bv = (const float*)d_in[6];
  const float* wo = (const float*)d_in[7];
  const float* bo = (const float*)d_in[8];
  float* out = (float*)d_out;

  char* ws = (char*)d_ws;
  ushort* xb     = (ushort*)(ws);              // 16 MB  x as bf16 (M x K)
  ushort* wt_qkv = (ushort*)(ws + 16777216);   // 6 MB   [wq|wk|wv]^T (3072 x 1024)
  ushort* wt_o   = (ushort*)(ws + 23068672);   // 2 MB   wo^T
  ushort* qb     = (ushort*)(ws + 25165824);   // 16 MB  Q (B,H,T,HD), pre-scaled
  ushort* kb     = (ushort*)(ws + 41943040);   // 16 MB  K (B,H,T,HD)
  ushort* vtb    = (ushort*)(ws + 58720256);   // 16 MB  V (B,H,HD,T)
  ushort* ob     = (ushort*)(ws + 75497472);   // 16 MB  attn out (B,T,D)

  cast_x_kernel<<<8192, 256, 0, stream>>>(x, xb);
  transpose_w_kernel<<<dim3(32, 32, 4), 256, 0, stream>>>(wq, wk, wv, wo, wt_qkv, wt_o);
  gemm_kernel<<<dim3(24, 64), 256, 0, stream>>>(xb, wt_qkv, 0, bq, bk, bv, qb, kb, vtb, nullptr);
  flash_kernel<<<dim3(16, 64), 256, 0, stream>>>(qb, kb, vtb, ob);
  gemm_kernel<<<dim3(8, 64), 256, 0, stream>>>(ob, wt_o, 1, bo, nullptr, nullptr,
                                               nullptr, nullptr, nullptr, out);
}